// Round 1
// baseline (2796.559 us; speedup 1.0000x reference)
//
#include <hip/hip_runtime.h>
#include <hip/hip_bf16.h>

// Problem: N=2048, F_IN=128, F_OUT=64
// out[j,f] = sum_{i,k} A[j,i] H[i,f] mh[i,k] H[k,f] mf[j,k],  H = X@W + b
// Strategy: per (f, j-tile) block: B_f = (A . diag(H_f)) @ mh via fp16 MFMA,
// fused epilogue out[j,f] += B_f[j,k] * mf[j,k] * H[k,f] (linear => fusable).

typedef __attribute__((ext_vector_type(8))) _Float16 f16x8;
typedef __attribute__((ext_vector_type(4))) _Float16 f16x4;
typedef __attribute__((ext_vector_type(4))) float f32x4;

#define N 2048
#define FOUT 64
#define FIN 128

// ---------------- prep kernels ----------------

// H[i,f] = X[i,:] @ W[:,f] + b[f]; store transposed HT[f][i] fp32 and fp16.
__global__ __launch_bounds__(256) void k_h(const float* __restrict__ X,
                                           const float* __restrict__ W,
                                           const float* __restrict__ bias,
                                           float* __restrict__ HT,
                                           _Float16* __restrict__ HTh) {
    __shared__ float Ws[FIN * FOUT];   // 32 KB
    __shared__ float Xs[4 * FIN];      // 2 KB
    int t = threadIdx.x;
#pragma unroll
    for (int s = 0; s < 32; ++s) Ws[t + 256 * s] = W[t + 256 * s];
    int i0 = blockIdx.x * 4;
#pragma unroll
    for (int s = 0; s < 2; ++s) { int idx = t + 256 * s; Xs[idx] = X[(size_t)i0 * FIN + idx]; }
    __syncthreads();
    int f = t & 63, il = t >> 6;
    float h = bias[f];
#pragma unroll
    for (int p = 0; p < FIN; ++p) h = fmaf(Xs[il * FIN + p], Ws[p * FOUT + f], h);
    int i = i0 + il;
    HT[f * N + i] = h;
    HTh[f * N + i] = (_Float16)h;
}

// A (fp32 row-major) -> fp16 same layout
__global__ __launch_bounds__(256) void k_a2h(const float* __restrict__ A,
                                             _Float16* __restrict__ Ah) {
    int g = blockIdx.x * 256 + threadIdx.x;   // one float4 per thread, N*N/4 total
    float4 v = ((const float4*)A)[g];
    f16x4 o;
    o[0] = (_Float16)v.x; o[1] = (_Float16)v.y; o[2] = (_Float16)v.z; o[3] = (_Float16)v.w;
    ((f16x4*)Ah)[g] = o;
}

// mh[i][k] fp32 -> mhT[k][i] fp16 (transposed), 64x64 LDS tiles
__global__ __launch_bounds__(256) void k_mht(const float* __restrict__ mh,
                                             _Float16* __restrict__ mhT) {
    __shared__ float tile[64][65];
    int t = threadIdx.x;
    int bx = blockIdx.x & 31;   // k tile
    int by = blockIdx.x >> 5;   // i tile
#pragma unroll
    for (int s = 0; s < 16; ++s) {
        int lin = t + 256 * s;
        int r = lin >> 6, c = lin & 63;           // r = i-local, c = k-local
        tile[r][c] = mh[(size_t)(by * 64 + r) * N + bx * 64 + c];
    }
    __syncthreads();
#pragma unroll
    for (int s = 0; s < 16; ++s) {
        int lin = t + 256 * s;
        int kr = lin >> 6, ic = lin & 63;         // kr = k-local, ic = i-local
        mhT[(size_t)(bx * 64 + kr) * N + by * 64 + ic] = (_Float16)tile[ic][kr];
    }
}

// ---------------- main kernel ----------------
// grid: 1024 blocks = 64 f * 16 j-tiles; 256 threads (4 waves).
// Block computes out[jbase..jbase+127, f].
// Wave layout: wj=(wave&1)*64 (j half), wk=(wave>>1)*64 (k half of 128-k tile).
#define BK 64

__global__ __launch_bounds__(256) void k_main(const float* __restrict__ mf,
                                              const float* __restrict__ HT,
                                              const _Float16* __restrict__ HTh,
                                              const _Float16* __restrict__ Ah,
                                              const _Float16* __restrict__ mhT,
                                              float* __restrict__ out) {
    // +8 halves pad: rows stay 16B-multiples (144B), b128 reads conflict-optimal
    __shared__ _Float16 lds_a[128][BK + 8];   // A_f tile [j][i]
    __shared__ _Float16 lds_b[128][BK + 8];   // mhT tile [k][i]
    __shared__ float red[4][64];

    int t = threadIdx.x;
    int f = blockIdx.x >> 4;
    int jbase = (blockIdx.x & 15) << 7;
    int wave = t >> 6, lane = t & 63, quad = lane >> 4, l16 = lane & 15;
    int wj = (wave & 1) << 6, wk = (wave >> 1) << 6;

    int srow = t >> 3;   // 0..31 staging row
    int scol = t & 7;    // 0..7 staging 8-elem chunk

    float outp[4][4];    // [j-subtile][r] partial outputs (post lane-reduce)
#pragma unroll
    for (int a = 0; a < 4; ++a)
#pragma unroll
        for (int b = 0; b < 4; ++b) outp[a][b] = 0.f;

    for (int ktile = 0; ktile < 16; ++ktile) {
        int kbase = ktile << 7;
        f32x4 acc[4][4];
#pragma unroll
        for (int a = 0; a < 4; ++a)
#pragma unroll
            for (int b = 0; b < 4; ++b) acc[a][b] = (f32x4){0.f, 0.f, 0.f, 0.f};

        for (int ibase = 0; ibase < N; ibase += BK) {
            __syncthreads();
            // stage A_f = A_h * H_h (pk_mul) and mhT (straight copy)
            f16x8 hv = *(const f16x8*)&HTh[f * N + ibase + scol * 8];
#pragma unroll
            for (int s = 0; s < 4; ++s) {
                int row = srow + 32 * s;
                f16x8 av = *(const f16x8*)&Ah[(size_t)(jbase + row) * N + ibase + scol * 8];
                *(f16x8*)&lds_a[row][scol * 8] = av * hv;
                f16x8 bv = *(const f16x8*)&mhT[(size_t)(kbase + row) * N + ibase + scol * 8];
                *(f16x8*)&lds_b[row][scol * 8] = bv;
            }
            __syncthreads();
#pragma unroll
            for (int istep = 0; istep < BK; istep += 32) {
                f16x8 afr[4], bfr[4];
#pragma unroll
                for (int x = 0; x < 4; ++x)
                    afr[x] = *(const f16x8*)&lds_a[wj + x * 16 + l16][istep + quad * 8];
#pragma unroll
                for (int x = 0; x < 4; ++x)
                    bfr[x] = *(const f16x8*)&lds_b[wk + x * 16 + l16][istep + quad * 8];
#pragma unroll
                for (int jj = 0; jj < 4; ++jj)
#pragma unroll
                    for (int kk = 0; kk < 4; ++kk)
                        acc[jj][kk] = __builtin_amdgcn_mfma_f32_16x16x32_f16(
                            afr[jj], bfr[kk], acc[jj][kk], 0, 0, 0);
            }
        }
        // epilogue: out[j,f] += sum_k acc * mf[j,k] * H[k,f]
#pragma unroll
        for (int jj = 0; jj < 4; ++jj) {
            float tmp[4] = {0.f, 0.f, 0.f, 0.f};
#pragma unroll
            for (int kk = 0; kk < 4; ++kk) {
                int kg = kbase + wk + kk * 16 + l16;
                float hk = HT[f * N + kg];
                int jrow = jbase + wj + jj * 16 + quad * 4;
#pragma unroll
                for (int r = 0; r < 4; ++r) {
                    float w = mf[(size_t)(jrow + r) * N + kg] * hk;
                    tmp[r] = fmaf(acc[jj][kk][r], w, tmp[r]);
                }
            }
#pragma unroll
            for (int r = 0; r < 4; ++r) {
                float v = tmp[r];
                v += __shfl_xor(v, 1);
                v += __shfl_xor(v, 2);
                v += __shfl_xor(v, 4);
                v += __shfl_xor(v, 8);
                outp[jj][r] += v;   // identical across l16 lanes (butterfly)
            }
        }
    }

    // cross-wave reduce (waves 0&2 cover j 0..63; 1&3 cover j 64..127)
    if (l16 == 0) {
#pragma unroll
        for (int jj = 0; jj < 4; ++jj)
#pragma unroll
            for (int r = 0; r < 4; ++r)
                red[wave][jj * 16 + quad * 4 + r] = outp[jj][r];
    }
    __syncthreads();
    if (t < 128) {
        int j = t;
        float v = (j < 64) ? (red[0][j] + red[2][j])
                           : (red[1][j - 64] + red[3][j - 64]);
        out[(size_t)(jbase + j) * FOUT + f] = v;
    }
}

// ---------------- launch ----------------
extern "C" void kernel_launch(void* const* d_in, const int* in_sizes, int n_in,
                              void* d_out, int out_size, void* d_ws, size_t ws_size,
                              hipStream_t stream) {
    const float* X    = (const float*)d_in[0];   // [2048,128]
    const float* A    = (const float*)d_in[1];   // [2048,2048]
    const float* mf   = (const float*)d_in[2];   // [2048,2048]
    const float* mh   = (const float*)d_in[3];   // [2048,2048]
    const float* W    = (const float*)d_in[4];   // [128,64]
    const float* bias = (const float*)d_in[5];   // [64]
    float* out = (float*)d_out;                  // [2048,64]

    // workspace layout (~17 MB total)
    float*    HT  = (float*)d_ws;                                  // 64*2048 fp32
    _Float16* HTh = (_Float16*)((char*)d_ws + 524288);             // 64*2048 fp16
    _Float16* Ah  = (_Float16*)((char*)d_ws + 1048576);            // 2048*2048 fp16
    _Float16* mhT = (_Float16*)((char*)d_ws + 1048576 + 8388608);  // 2048*2048 fp16 (transposed)

    k_h<<<N / 4, 256, 0, stream>>>(X, W, bias, HT, HTh);
    k_a2h<<<(N * N / 4) / 256, 256, 0, stream>>>(A, Ah);
    k_mht<<<(N / 64) * (N / 64), 256, 0, stream>>>(mh, mhT);
    k_main<<<64 * (N / 128), 256, 0, stream>>>(mf, HT, HTh, Ah, mhT, out);
}

// Round 2
// 1015.581 us; speedup vs baseline: 2.7537x; 2.7537x over previous
//
#include <hip/hip_runtime.h>
#include <hip/hip_bf16.h>

// Problem: N=2048, F_IN=128, F_OUT=64
// out[j,f] = sum_{i,k} A[j,i] H[i,f] mh[i,k] H[k,f] mf[j,k],  H = X@W + b
// R2: Fb=2 f-values per block (f-independent LDS tiles, H-scale at fragment
// read), global_load_lds width-16 staging with XOR chunk swizzle, double
// buffered issue-after-barrier. 512 blocks = exactly 2/CU resident.

typedef __attribute__((ext_vector_type(8))) _Float16 f16x8;
typedef __attribute__((ext_vector_type(4))) _Float16 f16x4;
typedef __attribute__((ext_vector_type(4))) float f32x4;

#define N 2048
#define FOUT 64
#define FIN 128
#define BI 64          // i-tile per stage
#define NIT 512        // 16 ktiles * 32 i-steps

__device__ __forceinline__ void gl_lds16(const _Float16* g, _Float16* l) {
    __builtin_amdgcn_global_load_lds(
        (const __attribute__((address_space(1))) void*)g,
        (__attribute__((address_space(3))) void*)l, 16, 0, 0);
}

// ---------------- prep kernels ----------------

__global__ __launch_bounds__(256) void k_h(const float* __restrict__ X,
                                           const float* __restrict__ W,
                                           const float* __restrict__ bias,
                                           float* __restrict__ HT,
                                           _Float16* __restrict__ HTh) {
    __shared__ float Ws[FIN * FOUT];
    __shared__ float Xs[4 * FIN];
    int t = threadIdx.x;
#pragma unroll
    for (int s = 0; s < 32; ++s) Ws[t + 256 * s] = W[t + 256 * s];
    int i0 = blockIdx.x * 4;
#pragma unroll
    for (int s = 0; s < 2; ++s) { int idx = t + 256 * s; Xs[idx] = X[(size_t)i0 * FIN + idx]; }
    __syncthreads();
    int f = t & 63, il = t >> 6;
    float h = bias[f];
#pragma unroll
    for (int p = 0; p < FIN; ++p) h = fmaf(Xs[il * FIN + p], Ws[p * FOUT + f], h);
    int i = i0 + il;
    HT[f * N + i] = h;
    HTh[f * N + i] = (_Float16)h;
}

__global__ __launch_bounds__(256) void k_a2h(const float* __restrict__ A,
                                             _Float16* __restrict__ Ah) {
    int g = blockIdx.x * 256 + threadIdx.x;
    float4 v = ((const float4*)A)[g];
    f16x4 o;
    o[0] = (_Float16)v.x; o[1] = (_Float16)v.y; o[2] = (_Float16)v.z; o[3] = (_Float16)v.w;
    ((f16x4*)Ah)[g] = o;
}

__global__ __launch_bounds__(256) void k_mht(const float* __restrict__ mh,
                                             _Float16* __restrict__ mhT) {
    __shared__ float tile[64][65];
    int t = threadIdx.x;
    int bx = blockIdx.x & 31;
    int by = blockIdx.x >> 5;
#pragma unroll
    for (int s = 0; s < 16; ++s) {
        int lin = t + 256 * s;
        int r = lin >> 6, c = lin & 63;
        tile[r][c] = mh[(size_t)(by * 64 + r) * N + bx * 64 + c];
    }
    __syncthreads();
#pragma unroll
    for (int s = 0; s < 16; ++s) {
        int lin = t + 256 * s;
        int kr = lin >> 6, ic = lin & 63;
        mhT[(size_t)(bx * 64 + kr) * N + by * 64 + ic] = (_Float16)tile[ic][kr];
    }
}

// ---------------- main kernel ----------------
// grid 512 = 16 jtiles (bid>>5) * 32 fgroups (bid&31); block = 128j x 128k x 2f.
// Wave w: wj=(w&1)*64, wk=(w>>1)*64; per-wave 64x64 per f.
// LDS tile row = 64 halves = 8 chunks of 16B; phys_chunk = log_chunk ^ (row&7).
__global__ __launch_bounds__(256, 2) void k_main(const float* __restrict__ mf,
                                                 const float* __restrict__ HT,
                                                 const _Float16* __restrict__ HTh,
                                                 const _Float16* __restrict__ Ah,
                                                 const _Float16* __restrict__ mhT,
                                                 float* __restrict__ out) {
    __shared__ _Float16 tiles[2][2][128 * BI];  // [buf][a=0/b=1][row*64+..] 64KB
    __shared__ _Float16 hbuf[2][N];             // H fp16 rows for f0,f1: 8KB
    __shared__ float red[2][4][64];             // 2KB

    int t = threadIdx.x;
    int jbase = (blockIdx.x >> 5) << 7;
    int f0 = (blockIdx.x & 31) << 1;
    int w = t >> 6, lane = t & 63, q = lane >> 4, l16 = lane & 15;
    int wj = (w & 1) << 6, wk = (w >> 1) << 6;

    // --- stage H rows (once) ---
#pragma unroll
    for (int s = 0; s < 2; ++s) {
        int idx = t + 256 * s;                // 0..511 ; fi=idx>>8, chunk=idx&255
        ((f16x8*)hbuf)[idx] = *(const f16x8*)&HTh[(size_t)(f0 + (idx >> 8)) * N + (idx & 255) * 8];
    }

    // --- staging voffsets (global_load_lds: lane l -> ldsbase + l*16) ---
    int lrow = lane >> 3;                      // row within 8-row call
    int lchunk = (lane & 7) ^ lrow;            // logical chunk (XOR swizzle)
    // halves offsets, call c adds c*8*N, i-step adds ibase
    int a_base = (jbase + w * 32 + lrow) * N + lchunk * 8;
    int b_base = (w * 32 + lrow) * N + lchunk * 8;   // + kbase*N per ktile
    int lds_w = w * 2048;                      // (w*32 rows)*64 halves

    float outp[2][4][4];
#pragma unroll
    for (int fi = 0; fi < 2; ++fi)
#pragma unroll
        for (int a = 0; a < 4; ++a)
#pragma unroll
            for (int b = 0; b < 4; ++b) outp[fi][a][b] = 0.f;

    // --- prefetch iteration 0 ---
    {
        const _Float16* pa = Ah + a_base;
        const _Float16* pb = mhT + b_base;
        _Float16* la = &tiles[0][0][lds_w];
        _Float16* lb = &tiles[0][1][lds_w];
#pragma unroll
        for (int c = 0; c < 4; ++c) {
            gl_lds16(pa + c * 8 * N, la + c * 512);
            gl_lds16(pb + c * 8 * N, lb + c * 512);
        }
    }

    f32x4 acc[2][4][4];
#pragma unroll
    for (int fi = 0; fi < 2; ++fi)
#pragma unroll
        for (int a = 0; a < 4; ++a)
#pragma unroll
            for (int b = 0; b < 4; ++b) acc[fi][a][b] = (f32x4){0.f, 0.f, 0.f, 0.f};

    for (int it = 0; it < NIT; ++it) {
        int buf = it & 1;
        int ibase = (it & 31) << 6;
        int kbase = (it >> 5) << 7;

        __syncthreads();   // drains prefetch(it) [vmcnt0] + frees other buffer

        // --- prefetch it+1 into other buffer (overlaps compute below) ---
        if (it + 1 < NIT) {
            int ib2 = ((it + 1) & 31) << 6;
            int kt2 = (it + 1) >> 5;
            const _Float16* pa = Ah + a_base + ib2;
            const _Float16* pb = mhT + b_base + kt2 * 128 * N + ib2;
            _Float16* la = &tiles[buf ^ 1][0][lds_w];
            _Float16* lb = &tiles[buf ^ 1][1][lds_w];
#pragma unroll
            for (int c = 0; c < 4; ++c) {
                gl_lds16(pa + c * 8 * N, la + c * 512);
                gl_lds16(pb + c * 8 * N, lb + c * 512);
            }
        }

        // --- compute from tiles[buf] ---
        const _Float16* ta = tiles[buf][0];
        const _Float16* tb = tiles[buf][1];
#pragma unroll
        for (int s = 0; s < 2; ++s) {
            f16x8 ar[4], br[4];
#pragma unroll
            for (int x = 0; x < 4; ++x) {
                int row = wj + x * 16 + l16;
                ar[x] = *(const f16x8*)&ta[row * 64 + (((q + 4 * s) ^ (l16 & 7)) * 8)];
            }
#pragma unroll
            for (int x = 0; x < 4; ++x) {
                int row = wk + x * 16 + l16;
                br[x] = *(const f16x8*)&tb[row * 64 + (((q + 4 * s) ^ (l16 & 7)) * 8)];
            }
            f16x8 h0 = *(const f16x8*)&hbuf[0][ibase + s * 32 + q * 8];
            f16x8 h1 = *(const f16x8*)&hbuf[1][ibase + s * 32 + q * 8];
#pragma unroll
            for (int jj = 0; jj < 4; ++jj) {
                f16x8 a0 = ar[jj] * h0;
                f16x8 a1 = ar[jj] * h1;
#pragma unroll
                for (int kk = 0; kk < 4; ++kk) {
                    acc[0][jj][kk] = __builtin_amdgcn_mfma_f32_16x16x32_f16(a0, br[kk], acc[0][jj][kk], 0, 0, 0);
                    acc[1][jj][kk] = __builtin_amdgcn_mfma_f32_16x16x32_f16(a1, br[kk], acc[1][jj][kk], 0, 0, 0);
                }
            }
        }

        // --- per-ktile epilogue: fold k into out-partials ---
        if ((it & 31) == 31) {
#pragma unroll
            for (int jj = 0; jj < 4; ++jj) {
                float t0[4] = {0.f, 0.f, 0.f, 0.f};
                float t1[4] = {0.f, 0.f, 0.f, 0.f};
#pragma unroll
                for (int kk = 0; kk < 4; ++kk) {
                    int kg = kbase + wk + kk * 16 + l16;
                    float hk0 = HT[f0 * N + kg];
                    float hk1 = HT[(f0 + 1) * N + kg];
                    int jrow = jbase + wj + jj * 16 + q * 4;
#pragma unroll
                    for (int r = 0; r < 4; ++r) {
                        float m = mf[(size_t)(jrow + r) * N + kg];
                        t0[r] = fmaf(acc[0][jj][kk][r], m * hk0, t0[r]);
                        t1[r] = fmaf(acc[1][jj][kk][r], m * hk1, t1[r]);
                    }
                }
#pragma unroll
                for (int r = 0; r < 4; ++r) {
                    float v0 = t0[r], v1 = t1[r];
                    v0 += __shfl_xor(v0, 1); v1 += __shfl_xor(v1, 1);
                    v0 += __shfl_xor(v0, 2); v1 += __shfl_xor(v1, 2);
                    v0 += __shfl_xor(v0, 4); v1 += __shfl_xor(v1, 4);
                    v0 += __shfl_xor(v0, 8); v1 += __shfl_xor(v1, 8);
                    outp[0][jj][r] += v0;
                    outp[1][jj][r] += v1;
                }
            }
#pragma unroll
            for (int fi = 0; fi < 2; ++fi)
#pragma unroll
                for (int a = 0; a < 4; ++a)
#pragma unroll
                    for (int b = 0; b < 4; ++b) acc[fi][a][b] = (f32x4){0.f, 0.f, 0.f, 0.f};
        }
    }

    // --- cross-wave reduce + store ---
    if (l16 == 0) {
#pragma unroll
        for (int fi = 0; fi < 2; ++fi)
#pragma unroll
            for (int jj = 0; jj < 4; ++jj)
#pragma unroll
                for (int r = 0; r < 4; ++r)
                    red[fi][w][jj * 16 + q * 4 + r] = outp[fi][jj][r];
    }
    __syncthreads();
    if (t < 128) {
        int j = t;
#pragma unroll
        for (int fi = 0; fi < 2; ++fi) {
            float v = (j < 64) ? (red[fi][0][j] + red[fi][2][j])
                               : (red[fi][1][j - 64] + red[fi][3][j - 64]);
            out[(size_t)(jbase + j) * FOUT + f0 + fi] = v;
        }
    }
}

// ---------------- launch ----------------
extern "C" void kernel_launch(void* const* d_in, const int* in_sizes, int n_in,
                              void* d_out, int out_size, void* d_ws, size_t ws_size,
                              hipStream_t stream) {
    const float* X    = (const float*)d_in[0];
    const float* A    = (const float*)d_in[1];
    const float* mf   = (const float*)d_in[2];
    const float* mh   = (const float*)d_in[3];
    const float* W    = (const float*)d_in[4];
    const float* bias = (const float*)d_in[5];
    float* out = (float*)d_out;

    float*    HT  = (float*)d_ws;
    _Float16* HTh = (_Float16*)((char*)d_ws + 524288);
    _Float16* Ah  = (_Float16*)((char*)d_ws + 1048576);
    _Float16* mhT = (_Float16*)((char*)d_ws + 1048576 + 8388608);

    k_h<<<N / 4, 256, 0, stream>>>(X, W, bias, HT, HTh);
    k_a2h<<<(N * N / 4) / 256, 256, 0, stream>>>(A, Ah);
    k_mht<<<(N / 64) * (N / 64), 256, 0, stream>>>(mh, mhT);
    k_main<<<16 * 32, 256, 0, stream>>>(mf, HT, HTh, Ah, mhT, out);
}